// Round 13
// baseline (142.004 us; speedup 1.0000x reference)
//
#include <hip/hip_runtime.h>
#include <hip/hip_bf16.h>

typedef __attribute__((ext_vector_type(8))) __bf16 bf16x8;
typedef __attribute__((ext_vector_type(16))) float f32x16;
typedef __attribute__((ext_vector_type(4))) unsigned int u32x4;

#define SCALE_L2E 14.4269504088896f // 10 * log2(e)
#define NTOT 32768

#define AS_GLOBAL __attribute__((address_space(1)))
#define AS_LDS    __attribute__((address_space(3)))

__device__ inline void async_copy16(const void* g, void* l) {
    __builtin_amdgcn_global_load_lds((const AS_GLOBAL void*)g, (AS_LDS void*)l, 16, 0, 0);
}

// ---------------------------------------------------------------------------
// bf16 pack helpers (RNE)
// ---------------------------------------------------------------------------
__device__ inline unsigned int f2bf(float f) {
    unsigned int u = __builtin_bit_cast(unsigned int, f);
    u += 0x7fffu + ((u >> 16) & 1u);
    return u >> 16;
}

__device__ inline uint4 pack8(float4 x, float4 y, float s) {
    uint4 r;
    r.x = f2bf(x.x * s) | (f2bf(x.y * s) << 16);
    r.y = f2bf(x.z * s) | (f2bf(x.w * s) << 16);
    r.z = f2bf(y.x * s) | (f2bf(y.y * s) << 16);
    r.w = f2bf(y.z * s) | (f2bf(y.w * s) << 16);
    return r;
}

__device__ inline float dot8(float4 x, float4 y) {
    return x.x*y.x + x.y*y.y + x.z*y.z + x.w*y.w;
}

// ---------------------------------------------------------------------------
// Kernel 1: L2-normalize -> bf16 FRAGMENT-MAJOR + fp32 diag partials.
// E1 is PRE-SCALED by 10*log2(e) so gemm's epilogue is exp2(acc).
// Coalesced E-stores via 32KB XOR-swizzled LDS transpose (r10, -13.5us).
// ---------------------------------------------------------------------------
__global__ __launch_bounds__(256) void nrm_kernel(
        const float* __restrict__ A, const float* __restrict__ B,
        uint4* __restrict__ E1f, uint4* __restrict__ E2f,
        float* __restrict__ diagPart, float* __restrict__ scalars,
        unsigned int* __restrict__ counter) {
    __shared__ uint4 E1lds[1024];   // 16 KB
    __shared__ uint4 E2lds[1024];   // 16 KB
    __shared__ float part[4];

    const int tid = threadIdx.x, w = tid >> 6, l = tid & 63;
    const int q = l & 31, h = l >> 5;
    const int wid = blockIdx.x * 4 + w;            // 0..4095, 8 rows each

    const float4* A4 = (const float4*)A + ((size_t)wid * 8 + h) * 64 + q * 2;
    const float4* B4 = (const float4*)B + ((size_t)wid * 8 + h) * 64 + q * 2;

    float4 a[8], bb[8];
    #pragma unroll
    for (int i = 0; i < 4; ++i) {                  // all loads up front (MLP)
        a[2*i]    = A4[i * 128];
        a[2*i+1]  = A4[i * 128 + 1];
        bb[2*i]   = B4[i * 128];
        bb[2*i+1] = B4[i * 128 + 1];
    }

    float ddAcc = 0.f;
    #pragma unroll
    for (int i = 0; i < 4; ++i) {
        float sa = dot8(a[2*i], a[2*i]) + dot8(a[2*i+1], a[2*i+1]);
        float sb = dot8(bb[2*i], bb[2*i]) + dot8(bb[2*i+1], bb[2*i+1]);
        float dd = dot8(a[2*i], bb[2*i]) + dot8(a[2*i+1], bb[2*i+1]);
        #pragma unroll
        for (int off = 1; off <= 16; off <<= 1) {
            sa += __shfl_xor(sa, off);
            sb += __shfl_xor(sb, off);
            dd += __shfl_xor(dd, off);
        }
        const float ia = 1.0f / fmaxf(sqrtf(sa), 1e-12f);
        const float ib = 1.0f / fmaxf(sqrtf(sb), 1e-12f);
        if (q == 0) ddAcc += dd * ia * ib * 10.0f;

        // LDS transpose staging: idx within this block's 32-row group
        const int row32 = w * 8 + i * 2 + h;                 // 0..31
        const int idx   = (q >> 1) * 64 + (q & 1) * 32 + row32;
        const int idxs  = idx ^ ((idx >> 5) & 7);            // bank swizzle
        E1lds[idxs] = pack8(a[2*i], a[2*i+1], ia * SCALE_L2E);  // pre-scaled
        E2lds[idxs] = pack8(bb[2*i], bb[2*i+1], ib);
    }

    #pragma unroll
    for (int off = 1; off <= 32; off <<= 1) ddAcc += __shfl_xor(ddAcc, off);
    if (l == 0) part[w] = ddAcc;
    __syncthreads();   // part[] + E-lds complete

    // coalesced write-out: this block's group is uint4[blockIdx*1024 ..)
    {
        uint4* g1 = E1f + (size_t)blockIdx.x * 1024;
        uint4* g2 = E2f + (size_t)blockIdx.x * 1024;
        #pragma unroll
        for (int j = 0; j < 4; ++j) {
            const int t = j * 256 + tid;
            const int ts = t ^ ((t >> 5) & 7);
            g1[t] = E1lds[ts];
            g2[t] = E2lds[ts];
        }
    }

    if (tid == 0) diagPart[blockIdx.x] = part[0] + part[1] + part[2] + part[3];
    if (blockIdx.x == 0 && tid == 0) { scalars[0] = 0.f; *counter = 0u; }
}

// ---------------------------------------------------------------------------
// Kernel 2: fused GEMM + exp + row/col partials. 512 blocks x 512 THREADS.
// Block: 256 rows x 512 cols; EIGHT waves x 32 rows each.
//
// 4-WAVES/SIMD REDESIGN (the r12 ledger: per-wave total regs ~256 -> only
// 2 waves/SIMD -> MfmaUtil stuck at 30% with both streams stalling on the
// same lgkm/barrier). New budget per wave:
//   AGPR 64: af[16] forced by asm "a" constraint (r4: compiler won't do it
//            itself, spills instead; r8/r9: "a" pinning is correct)
//   VGPR 64: ONE f32x16 "+v" acc (16, immediate epilogue -- r9's spill was
//            4 fragmenting tuples) + rowAcc 16 + temps (~25); cap via
//            __launch_bounds__(512,4)
// -> 128 total/wave = 4 waves/SIMD, 16 waves/CU: TLP hides epi VALU and
// ds_read latency instead of the manual pipeline. Cost: each bfrag feeds
// 1 MFMA (LDS volume 2x, ~20us floor) -- still far below the 42us it
// replaces. Counted-vmcnt staging kept: 16 steps x 32 cols, 3 bufs,
// 2-ahead, vmcnt(2). LDS 64 KB -> 2 blocks/CU.
// s_nop guards cover the asm-MFMA hazards (r8/r9 proven).
// ---------------------------------------------------------------------------
__global__ __launch_bounds__(512, 4) void gemm_kernel(
        const bf16x8* __restrict__ E1f, const uint4* __restrict__ E2f,
        float* __restrict__ colPart, float* __restrict__ rowPart) {
    __shared__ bf16x8 Bbuf[3][1024];   // 3 x 16 KB (32 cols each)
    __shared__ float colLDS[4096];     // 8 per-wave slices of 512 (16 KB)

    const int tid = threadIdx.x, w = tid >> 6, l = tid & 63;   // w 0..7
    const int b = blockIdx.x & 15;             // XCD = b&7 (L2 pinning)
    const int ct = (blockIdx.x >> 4) & 3, rt = blockIdx.x >> 6;

    for (int i = l; i < 512; i += 64) colLDS[w * 512 + i] = 0.f;

    const uint4* Bb = E2f + (size_t)b * 65536 + (size_t)ct * 16384 + l;

    // stage 32-col step s into Bbuf[s%3]; wave w covers 2 chunk-rows
    auto stage = [&](int s) {
        const uint4* src = Bb + (size_t)s * 1024 + (w * 2) * 64;
        #pragma unroll
        for (int j = 0; j < 2; ++j)
            async_copy16(src + j * 64, &Bbuf[s % 3][(w * 2 + j) * 64]);
    };

    stage(0);   // 2-deep prefetch queued first; A-loads land behind it
    stage(1);

    // A fragments: ONE 32-row tile per wave; pinned to AGPRs by the "a"
    // constraint on every MFMA use (v->a copies once at load time).
    const u32x4* Af = (const u32x4*)(E1f + (size_t)b * 65536
                                     + (size_t)(rt * 8 + w) * 1024) + l;
    u32x4 af[16];
    #pragma unroll
    for (int kt = 0; kt < 16; ++kt) af[kt] = Af[kt * 64];

    float rowAcc[16];
    #pragma unroll
    for (int r = 0; r < 16; ++r) rowAcc[r] = 0.f;

    // single-chain MFMA for one 32-col step (AGPR af, VGPR acc)
    auto chain = [&](f32x16& x, const bf16x8* Bf) {
        #pragma unroll
        for (int r = 0; r < 16; ++r) x[r] = 0.f;
        asm volatile("s_nop 1");            // v_mov acc-init -> MFMA read-C
        __builtin_amdgcn_s_setprio(1);
        #pragma unroll
        for (int kt = 0; kt < 16; ++kt) {
            u32x4 bv = __builtin_bit_cast(u32x4, Bf[kt * 64]);
            asm("v_mfma_f32_32x32x16_bf16 %0, %1, %2, %0"
                : "+v"(x) : "a"(af[kt]), "v"(bv));
        }
        __builtin_amdgcn_s_setprio(0);
        asm volatile("s_nop 7\ns_nop 7\ns_nop 1");  // MFMA -> VALU read
    };

    // immediate epilogue (32 rows x 32 cols per step)
    auto epi = [&](const f32x16& c, int slot) {
        float p = 0.f;
        #pragma unroll
        for (int r = 0; r < 16; ++r) {
            float e = __builtin_amdgcn_exp2f(c[r]);
            rowAcc[r] += e;
            p += e;
        }
        p += __shfl_xor(p, 32);                 // fold 16-row halves
        if (l < 32) colLDS[w * 512 + slot * 32 + l] += p;
    };

    f32x16 c;

    // 16 steps; counted vmcnt: stage(s) done, stage(s+1) in flight
    #pragma unroll 1
    for (int s = 0; s < 14; ++s) {
        asm volatile("s_waitcnt vmcnt(2)" ::: "memory");
        __builtin_amdgcn_s_barrier();
        stage(s + 2);
        chain(c, Bbuf[s % 3] + l);
        epi(c, s);
    }
    // step 14 (no more staging; stage(15) still in flight)
    asm volatile("s_waitcnt vmcnt(2)" ::: "memory");
    __builtin_amdgcn_s_barrier();
    chain(c, Bbuf[14 % 3] + l);
    epi(c, 14);
    // step 15 (final: full drain)
    asm volatile("s_waitcnt vmcnt(0)" ::: "memory");
    __builtin_amdgcn_s_barrier();
    chain(c, Bbuf[15 % 3] + l);
    epi(c, 15);

    // row sums: reduce across 32 column-lanes
    #pragma unroll
    for (int r = 0; r < 16; ++r) {
        #pragma unroll
        for (int off = 1; off <= 16; off <<= 1)
            rowAcc[r] += __shfl_xor(rowAcc[r], off);
    }
    if ((l & 31) == 0) {
        // C/D layout: row = (r&3) + 8*(r>>2) + 4*(lane>>5); plain stores
        float* rs = rowPart + (size_t)(b * 4 + ct) * 2048 + rt * 256 + w * 32 + 4 * (l >> 5);
        #pragma unroll
        for (int r = 0; r < 16; ++r) {
            const int rl = (r & 3) + 8 * (r >> 2);
            rs[rl] = rowAcc[r];
        }
    }

    __syncthreads();   // full barrier before cross-wave colLDS fold
    float* gcol = colPart + (size_t)((b * 4 + ct) * 8 + rt) * 512;
    {
        float scol = 0.f;          // 512 threads, one column each
        #pragma unroll
        for (int s = 0; s < 8; ++s) scol += colLDS[s * 512 + tid];
        gcol[tid] = scol;
    }
}

// ---------------------------------------------------------------------------
// Kernel 3: fold partials, sum logs, last block finalizes. 128 blocks
// (doubled parallelism; 1 column + 1 row per thread). gemm computes
// exp2(acc) (no -SCALE_L2E shift); each of the 2*32768 log terms is larger
// by exactly 10.0, cancelling the former "+ 20.0f".
// ---------------------------------------------------------------------------
__global__ __launch_bounds__(256) void fin_kernel(
        const float* __restrict__ colPart, const float* __restrict__ rowPart,
        const float* __restrict__ diagPart, float* __restrict__ scalars,
        unsigned int* __restrict__ counter, float* __restrict__ out) {
    const int tid = threadIdx.x;
    const int g = blockIdx.x * 256 + tid;
    // column g: b = g>>11, ct = (g>>9)&3, c = g&511
    const float* cp = colPart + (size_t)(((g >> 11) * 4 + ((g >> 9) & 3)) * 8) * 512 + (g & 511);
    float cs = 0.f;
    #pragma unroll
    for (int rt = 0; rt < 8; ++rt) cs += cp[rt * 512];
    // row g: b = g>>11, r = g&2047
    const float* rp = rowPart + (size_t)(g >> 11) * 4 * 2048 + (g & 2047);
    float rsum = rp[0] + rp[2048] + rp[4096] + rp[6144];
    float s = logf(cs) + logf(rsum);

    #pragma unroll
    for (int off = 1; off <= 32; off <<= 1) s += __shfl_xor(s, off);
    __shared__ float part[4];
    __shared__ unsigned int lastFlag;
    if ((tid & 63) == 0) part[tid >> 6] = s;
    __syncthreads();
    if (tid == 0) {
        atomicAdd(&scalars[0], part[0] + part[1] + part[2] + part[3]);
        __threadfence();
        lastFlag = (atomicAdd(counter, 1u) == 127u) ? 1u : 0u;
    }
    __syncthreads();
    if (lastFlag) {
        float d = diagPart[tid] + diagPart[tid + 256]
                + diagPart[tid + 512] + diagPart[tid + 768];
        #pragma unroll
        for (int off = 1; off <= 32; off <<= 1) d += __shfl_xor(d, off);
        if ((tid & 63) == 0) part[tid >> 6] = d;
        __syncthreads();
        if (tid == 0) {
            const float diag = part[0] + part[1] + part[2] + part[3];
            const float logSum = atomicAdd(&scalars[0], 0.f);  // coherent read
            out[0] = (logSum - 2.0f * diag) / (float)NTOT;
        }
    }
}

// ---------------------------------------------------------------------------
extern "C" void kernel_launch(void* const* d_in, const int* in_sizes, int n_in,
                              void* d_out, int out_size, void* d_ws, size_t ws_size,
                              hipStream_t stream) {
    const float* A = (const float*)d_in[0];
    const float* B = (const float*)d_in[1];

    char* w = (char*)d_ws;
    uint4* E1f = (uint4*)w;                                    // 16 MB
    uint4* E2f = (uint4*)(w + (size_t)16 * 1024 * 1024);       // 16 MB
    float* colPart = (float*)(w + (size_t)32 * 1024 * 1024);   // 262144 f (1 MB)
    float* rowPart = colPart + 262144;                         // 131072 f (0.5 MB)
    float* diagPart = rowPart + 131072;                        // 1024 f
    float* scalars = diagPart + 1024;                          // [logSum]
    unsigned int* counter = (unsigned int*)(scalars + 1);

    hipLaunchKernelGGL(nrm_kernel, dim3(1024), dim3(256), 0, stream,
                       A, B, E1f, E2f, diagPart, scalars, counter);
    hipLaunchKernelGGL(gemm_kernel, dim3(512), dim3(512), 0, stream,
                       (const bf16x8*)E1f, (const uint4*)E2f, colPart, rowPart);
    hipLaunchKernelGGL(fin_kernel, dim3(128), dim3(256), 0, stream,
                       colPart, rowPart, diagPart, scalars, counter, (float*)d_out);
}